// Round 1
// baseline (2658.714 us; speedup 1.0000x reference)
//
#include <hip/hip_runtime.h>

#define DIM 64

// cur/acc init: concat(user_emb, item_emb) -> cur, acc (float4-vectorized)
__global__ void lgcn_init(const float4* __restrict__ ue, const float4* __restrict__ ie,
                          float4* __restrict__ cur, float4* __restrict__ acc,
                          long long n_user_v4, long long total_v4) {
    long long idx = (long long)blockIdx.x * blockDim.x + threadIdx.x;
    long long stride = (long long)gridDim.x * blockDim.x;
    for (long long i = idx; i < total_v4; i += stride) {
        float4 v = (i < n_user_v4) ? ue[i] : ie[i - n_user_v4];
        cur[i] = v;
        acc[i] = v;
    }
}

// SpMM: for each edge e, lane d: next[rows[e]*64+d] += vals[e] * cur[cols[e]*64+d]
// One 64-lane wave handles one edge per iteration: rows/cols/vals loads are
// wave-uniform (broadcast), gather + atomics are 256B coalesced.
__global__ void lgcn_spmm(const float* __restrict__ vals,
                          const int* __restrict__ rows,
                          const int* __restrict__ cols,
                          const float* __restrict__ cur,
                          float* __restrict__ next,
                          long long nE) {
    long long tid = (long long)blockIdx.x * blockDim.x + threadIdx.x;
    long long stride = (long long)gridDim.x * blockDim.x;
    long long total = nE << 6;  // E * 64
    for (long long i = tid; i < total; i += stride) {
        long long e = i >> 6;
        int d = (int)(i & 63);
        int r = rows[e];
        int c = cols[e];
        float v = vals[e];
        float m = v * cur[((long long)c << 6) + d];
        atomicAdd(&next[((long long)r << 6) + d], m);
    }
}

__global__ void lgcn_acc_add(float4* __restrict__ acc, const float4* __restrict__ nxt,
                             long long total_v4) {
    long long idx = (long long)blockIdx.x * blockDim.x + threadIdx.x;
    long long stride = (long long)gridDim.x * blockDim.x;
    for (long long i = idx; i < total_v4; i += stride) {
        float4 a = acc[i];
        float4 b = nxt[i];
        a.x += b.x; a.y += b.y; a.z += b.z; a.w += b.w;
        acc[i] = a;
    }
}

__global__ void lgcn_acc_add_scale(float4* __restrict__ acc, const float4* __restrict__ nxt,
                                   float s, long long total_v4) {
    long long idx = (long long)blockIdx.x * blockDim.x + threadIdx.x;
    long long stride = (long long)gridDim.x * blockDim.x;
    for (long long i = idx; i < total_v4; i += stride) {
        float4 a = acc[i];
        float4 b = nxt[i];
        a.x = (a.x + b.x) * s; a.y = (a.y + b.y) * s;
        a.z = (a.z + b.z) * s; a.w = (a.w + b.w) * s;
        acc[i] = a;
    }
}

extern "C" void kernel_launch(void* const* d_in, const int* in_sizes, int n_in,
                              void* d_out, int out_size, void* d_ws, size_t ws_size,
                              hipStream_t stream) {
    const float* ue   = (const float*)d_in[0];
    const float* ie   = (const float*)d_in[1];
    const float* vals = (const float*)d_in[2];
    const int*   rows = (const int*)d_in[3];
    const int*   cols = (const int*)d_in[4];
    // d_in[5] = n_layers (device scalar). Grid shapes must be host-known;
    // the problem fixes n_layers = 3.
    const int n_layers = 3;

    const long long n_users = in_sizes[0] / DIM;
    const long long n_items = in_sizes[1] / DIM;
    const long long E       = in_sizes[2];
    const long long N       = n_users + n_items;
    const long long nElem   = N * DIM;            // 19.2M floats
    const long long nV4     = nElem / 4;
    const long long nUserV4 = (n_users * DIM) / 4;

    float* acc = (float*)d_out;                   // running sum lives in d_out
    float* cur = (float*)d_ws;                    // ping
    float* nxt = cur + nElem;                     // pong

    const int tb = 256;
    int gridInit = (int)((nV4 + tb - 1) / tb);
    if (gridInit > 4096) gridInit = 4096;
    lgcn_init<<<gridInit, tb, 0, stream>>>((const float4*)ue, (const float4*)ie,
                                           (float4*)cur, (float4*)acc, nUserV4, nV4);

    const int gridSpmm = 8192;                    // grid-stride over E*64 items
    int gridAcc = (int)((nV4 + tb - 1) / tb);
    if (gridAcc > 4096) gridAcc = 4096;

    for (int l = 0; l < n_layers; ++l) {
        hipMemsetAsync(nxt, 0, nElem * sizeof(float), stream);
        lgcn_spmm<<<gridSpmm, tb, 0, stream>>>(vals, rows, cols, cur, nxt, E);
        if (l == n_layers - 1) {
            lgcn_acc_add_scale<<<gridAcc, tb, 0, stream>>>(
                (float4*)acc, (const float4*)nxt, 1.0f / (float)(n_layers + 1), nV4);
        } else {
            lgcn_acc_add<<<gridAcc, tb, 0, stream>>>((float4*)acc, (const float4*)nxt, nV4);
        }
        float* t = cur; cur = nxt; nxt = t;
    }
}

// Round 2
// 1299.606 us; speedup vs baseline: 2.0458x; 2.0458x over previous
//
#include <hip/hip_runtime.h>

#define DIM 64
#define SCAN_T 256
#define SCAN_I 16
#define SCAN_CHUNK (SCAN_T * SCAN_I)

// ============================ CSR build ============================

__global__ void k_hist(const int* __restrict__ rows, int* __restrict__ deg, long long E) {
    long long i = (long long)blockIdx.x * blockDim.x + threadIdx.x;
    long long st = (long long)gridDim.x * blockDim.x;
    for (; i < E; i += st) atomicAdd(&deg[rows[i]], 1);
}

__global__ void k_scan1(const int* __restrict__ deg, int* __restrict__ partials, long long N) {
    long long base = (long long)blockIdx.x * SCAN_CHUNK + (long long)threadIdx.x * SCAN_I;
    int tsum = 0;
    for (int k = 0; k < SCAN_I; ++k) {
        long long i = base + k;
        if (i < N) tsum += deg[i];
    }
    __shared__ int s[SCAN_T];
    s[threadIdx.x] = tsum; __syncthreads();
    for (int o = SCAN_T / 2; o > 0; o >>= 1) {
        if (threadIdx.x < o) s[threadIdx.x] += s[threadIdx.x + o];
        __syncthreads();
    }
    if (threadIdx.x == 0) partials[blockIdx.x] = s[0];
}

__global__ void k_scan2(int* partials, int nb) {
    if (threadIdx.x == 0 && blockIdx.x == 0) {
        int run = 0;
        for (int i = 0; i < nb; ++i) { int v = partials[i]; partials[i] = run; run += v; }
    }
}

__global__ void k_scan3(const int* __restrict__ deg, const int* __restrict__ partials,
                        int* __restrict__ rp, int* __restrict__ cursor, long long N) {
    const int t = threadIdx.x;
    long long base = (long long)blockIdx.x * SCAN_CHUNK + (long long)t * SCAN_I;
    int local[SCAN_I];
    int tsum = 0;
    for (int k = 0; k < SCAN_I; ++k) {
        long long i = base + k;
        int d = (i < N) ? deg[i] : 0;
        local[k] = tsum;   // thread-local exclusive prefix
        tsum += d;
    }
    __shared__ int s[SCAN_T];
    s[t] = tsum; __syncthreads();
    for (int o = 1; o < SCAN_T; o <<= 1) {         // Hillis-Steele inclusive scan
        int v = (t >= o) ? s[t - o] : 0;
        __syncthreads();
        s[t] += v;
        __syncthreads();
    }
    int toff = partials[blockIdx.x] + (s[t] - tsum);  // block base + thread-exclusive
    for (int k = 0; k < SCAN_I; ++k) {
        long long i = base + k;
        if (i < N) {
            int v = toff + local[k];
            rp[i] = v;
            cursor[i] = v;
            if (i == N - 1) rp[N] = v + deg[i];
        }
    }
}

// deg (int) -> d_inv_sqrt (float), in place
__global__ void k_dinv(int* __restrict__ degbuf, long long N) {
    long long i = (long long)blockIdx.x * blockDim.x + threadIdx.x;
    if (i < N) {
        int d = degbuf[i];
        float r = (d > 0) ? rsqrtf((float)d) : 0.0f;
        ((float*)degbuf)[i] = r;
    }
}

__global__ void k_fill(const int* __restrict__ rows, const int* __restrict__ cols,
                       int* __restrict__ cursor, int* __restrict__ colso, long long E) {
    long long i = (long long)blockIdx.x * blockDim.x + threadIdx.x;
    long long st = (long long)gridDim.x * blockDim.x;
    for (; i < E; i += st) {
        int r = rows[i];
        int p = atomicAdd(&cursor[r], 1);
        colso[p] = cols[i];
    }
}

// ============================ fused CSR SpMM ============================
// One 64-lane wave per row; lane = embedding dim. Chunk-load up to 64 edge
// cols cooperatively, broadcast each via shfl, gather coalesced 256B rows.
// MODE 0: gather from concat(ue,ie); dst = s; acc = emb_row + s   (layer 1)
// MODE 1: gather from src;           dst = s; acc += s            (layer 2)
// MODE 2: gather from src;           no dst;  acc = (acc+s)*scale (layer 3)
template<int MODE>
__global__ void k_spmm(const int* __restrict__ rp, const int* __restrict__ colso,
                       const float* __restrict__ dinv,
                       const float* __restrict__ src,
                       const float* __restrict__ ue, const float* __restrict__ ie,
                       float* __restrict__ dst, float* __restrict__ accb,
                       long long N, long long NU, float scale) {
    const int lane = threadIdx.x & 63;
    long long row = (long long)blockIdx.x * (blockDim.x >> 6) + (threadIdx.x >> 6);
    if (row >= N) return;
    const int beg = rp[row], end = rp[row + 1];
    float s = 0.0f;
    for (int base = beg; base < end; base += 64) {
        int rem = end - base;
        int col = 0; float dc = 0.0f;
        if (lane < rem) { col = colso[base + lane]; dc = dinv[col]; }
        int m = rem < 64 ? rem : 64;
        for (int j = 0; j < m; ++j) {
            int   c = __shfl(col, j, 64);
            float w = __shfl(dc, j, 64);
            long long off = ((long long)c << 6) + lane;
            float g;
            if (MODE == 0) g = (c < (int)NU) ? ue[off] : ie[off - (NU << 6)];
            else           g = src[off];
            s = fmaf(w, g, s);
        }
    }
    s *= dinv[row];
    long long o = (row << 6) + lane;
    if (MODE == 0) {
        float e0 = (row < NU) ? ue[o] : ie[o - (NU << 6)];
        dst[o] = s;
        accb[o] = e0 + s;
    } else if (MODE == 1) {
        dst[o] = s;
        accb[o] += s;
    } else {
        accb[o] = (accb[o] + s) * scale;
    }
}

// ============================ fallback (atomic) ============================

__global__ void lgcn_init(const float4* __restrict__ ue, const float4* __restrict__ ie,
                          float4* __restrict__ cur, float4* __restrict__ acc,
                          long long n_user_v4, long long total_v4) {
    long long idx = (long long)blockIdx.x * blockDim.x + threadIdx.x;
    long long stride = (long long)gridDim.x * blockDim.x;
    for (long long i = idx; i < total_v4; i += stride) {
        float4 v = (i < n_user_v4) ? ue[i] : ie[i - n_user_v4];
        cur[i] = v;
        acc[i] = v;
    }
}

__global__ void lgcn_spmm(const float* __restrict__ vals, const int* __restrict__ rows,
                          const int* __restrict__ cols, const float* __restrict__ cur,
                          float* __restrict__ next, long long nE) {
    long long tid = (long long)blockIdx.x * blockDim.x + threadIdx.x;
    long long stride = (long long)gridDim.x * blockDim.x;
    long long total = nE << 6;
    for (long long i = tid; i < total; i += stride) {
        long long e = i >> 6;
        int d = (int)(i & 63);
        float m = vals[e] * cur[((long long)cols[e] << 6) + d];
        atomicAdd(&next[((long long)rows[e] << 6) + d], m);
    }
}

__global__ void lgcn_acc_add(float4* __restrict__ acc, const float4* __restrict__ nxt,
                             long long total_v4) {
    long long idx = (long long)blockIdx.x * blockDim.x + threadIdx.x;
    long long stride = (long long)gridDim.x * blockDim.x;
    for (long long i = idx; i < total_v4; i += stride) {
        float4 a = acc[i]; float4 b = nxt[i];
        a.x += b.x; a.y += b.y; a.z += b.z; a.w += b.w;
        acc[i] = a;
    }
}

__global__ void lgcn_acc_add_scale(float4* __restrict__ acc, const float4* __restrict__ nxt,
                                   float s, long long total_v4) {
    long long idx = (long long)blockIdx.x * blockDim.x + threadIdx.x;
    long long stride = (long long)gridDim.x * blockDim.x;
    for (long long i = idx; i < total_v4; i += stride) {
        float4 a = acc[i]; float4 b = nxt[i];
        a.x = (a.x + b.x) * s; a.y = (a.y + b.y) * s;
        a.z = (a.z + b.z) * s; a.w = (a.w + b.w) * s;
        acc[i] = a;
    }
}

// ============================ launch ============================

extern "C" void kernel_launch(void* const* d_in, const int* in_sizes, int n_in,
                              void* d_out, int out_size, void* d_ws, size_t ws_size,
                              hipStream_t stream) {
    const float* ue   = (const float*)d_in[0];
    const float* ie   = (const float*)d_in[1];
    const float* vals = (const float*)d_in[2];
    const int*   rows = (const int*)d_in[3];
    const int*   cols = (const int*)d_in[4];
    const int n_layers = 3;   // fixed by problem; grid shapes must be host-known

    const long long n_users = in_sizes[0] / DIM;
    const long long n_items = in_sizes[1] / DIM;
    const long long E       = in_sizes[2];
    const long long N       = n_users + n_items;
    const long long nElem   = N * DIM;
    const long long nV4     = nElem / 4;
    const long long nUserV4 = (n_users * DIM) / 4;

    float* acc = (float*)d_out;
    const int tb = 256;
    const int nb = (int)((N + SCAN_CHUNK - 1) / SCAN_CHUNK);

    // ws layout for CSR path
    size_t need = (size_t)(2 * nElem + N /*deg/dinv*/ + (N + 1) /*rp*/ + N /*cursor*/
                           + E /*colso*/ + nb + 64) * 4;

    if (ws_size >= need) {
        char* p = (char*)d_ws;
        float* buf0   = (float*)p;                 p += (size_t)nElem * 4;
        float* buf1   = (float*)p;                 p += (size_t)nElem * 4;
        int*   deg    = (int*)p;                   p += (size_t)N * 4;   // becomes dinv
        int*   rp     = (int*)p;                   p += (size_t)(N + 1) * 4;
        int*   cursor = (int*)p;                   p += (size_t)N * 4;
        int*   colso  = (int*)p;                   p += (size_t)E * 4;
        int*   partials = (int*)p;
        float* dinv = (float*)deg;

        hipMemsetAsync(deg, 0, (size_t)N * 4, stream);
        k_hist<<<2048, tb, 0, stream>>>(rows, deg, E);
        k_scan1<<<nb, SCAN_T, 0, stream>>>(deg, partials, N);
        k_scan2<<<1, 64, 0, stream>>>(partials, nb);
        k_scan3<<<nb, SCAN_T, 0, stream>>>(deg, partials, rp, cursor, N);
        k_dinv<<<(int)((N + tb - 1) / tb), tb, 0, stream>>>(deg, N);
        k_fill<<<2048, tb, 0, stream>>>(rows, cols, cursor, colso, E);

        const int WPB = tb / 64;                      // 4 rows per block
        const int gspmm = (int)((N + WPB - 1) / WPB);
        k_spmm<0><<<gspmm, tb, 0, stream>>>(rp, colso, dinv, nullptr, ue, ie,
                                            buf0, acc, N, n_users, 0.0f);
        k_spmm<1><<<gspmm, tb, 0, stream>>>(rp, colso, dinv, buf0, ue, ie,
                                            buf1, acc, N, n_users, 0.0f);
        k_spmm<2><<<gspmm, tb, 0, stream>>>(rp, colso, dinv, buf1, ue, ie,
                                            nullptr, acc, N, n_users,
                                            1.0f / (float)(n_layers + 1));
    } else {
        // fallback: atomic scatter path (round-1 kernel)
        float* cur = (float*)d_ws;
        float* nxt = cur + nElem;
        int gridInit = (int)((nV4 + tb - 1) / tb); if (gridInit > 4096) gridInit = 4096;
        lgcn_init<<<gridInit, tb, 0, stream>>>((const float4*)ue, (const float4*)ie,
                                               (float4*)cur, (float4*)acc, nUserV4, nV4);
        int gridAcc = gridInit;
        for (int l = 0; l < n_layers; ++l) {
            hipMemsetAsync(nxt, 0, (size_t)nElem * 4, stream);
            lgcn_spmm<<<8192, tb, 0, stream>>>(vals, rows, cols, cur, nxt, E);
            if (l == n_layers - 1) {
                lgcn_acc_add_scale<<<gridAcc, tb, 0, stream>>>(
                    (float4*)acc, (const float4*)nxt, 1.0f / (float)(n_layers + 1), nV4);
            } else {
                lgcn_acc_add<<<gridAcc, tb, 0, stream>>>((float4*)acc, (const float4*)nxt, nV4);
            }
            float* t = cur; cur = nxt; nxt = t;
        }
    }
}

// Round 3
// 962.190 us; speedup vs baseline: 2.7632x; 1.3507x over previous
//
#include <hip/hip_runtime.h>

#define DIM 64
#define CH 16384          // edges per chunk in sort passes
#define BROWS 512         // rows per bucket
#define BSH 9             // log2(BROWS)
#define CBITS 19          // bits for col index in packed word (N < 2^19)
#define CMASK ((1u << CBITS) - 1u)
#define SCAN_T 256
#define SCAN_I 16
#define SCAN_CHUNK (SCAN_T * SCAN_I)

// ===================== dense CSR build (counting sort) =====================

// Pass A: per-chunk bucket histogram (LDS), write cnt[b][chunk] (bucket-major)
__global__ void k_cnt(const int* __restrict__ rows, int* __restrict__ cnt,
                      int nchunks, int NB, long long E) {
    extern __shared__ int hist[];
    for (int b = threadIdx.x; b < NB; b += blockDim.x) hist[b] = 0;
    __syncthreads();
    long long beg = (long long)blockIdx.x * CH;
    long long end = beg + CH; if (end > E) end = E;
    for (long long i = beg + threadIdx.x; i < end; i += blockDim.x)
        atomicAdd(&hist[rows[i] >> BSH], 1);
    __syncthreads();
    for (int b = threadIdx.x; b < NB; b += blockDim.x)
        cnt[(long long)b * nchunks + blockIdx.x] = hist[b];
}

// Generic 3-pass exclusive scan (in place) over length L
__global__ void k_scanA(const int* __restrict__ in, int* __restrict__ partials, long long L) {
    long long base = (long long)blockIdx.x * SCAN_CHUNK + (long long)threadIdx.x * SCAN_I;
    int tsum = 0;
    for (int k = 0; k < SCAN_I; ++k) { long long i = base + k; if (i < L) tsum += in[i]; }
    __shared__ int s[SCAN_T];
    s[threadIdx.x] = tsum; __syncthreads();
    for (int o = SCAN_T / 2; o > 0; o >>= 1) {
        if (threadIdx.x < o) s[threadIdx.x] += s[threadIdx.x + o];
        __syncthreads();
    }
    if (threadIdx.x == 0) partials[blockIdx.x] = s[0];
}

__global__ void k_scanB(int* partials, int nb) {
    if (threadIdx.x == 0 && blockIdx.x == 0) {
        int run = 0;
        for (int i = 0; i < nb; ++i) { int v = partials[i]; partials[i] = run; run += v; }
    }
}

__global__ void k_scanC(int* __restrict__ data, const int* __restrict__ partials, long long L) {
    const int t = threadIdx.x;
    long long base = (long long)blockIdx.x * SCAN_CHUNK + (long long)t * SCAN_I;
    int local[SCAN_I]; int tsum = 0;
    for (int k = 0; k < SCAN_I; ++k) {
        long long i = base + k;
        int d = (i < L) ? data[i] : 0;
        local[k] = tsum; tsum += d;
    }
    __shared__ int s[SCAN_T];
    s[t] = tsum; __syncthreads();
    for (int o = 1; o < SCAN_T; o <<= 1) {
        int v = (t >= o) ? s[t - o] : 0;
        __syncthreads();
        s[t] += v;
        __syncthreads();
    }
    int toff = partials[blockIdx.x] + (s[t] - tsum);
    for (int k = 0; k < SCAN_I; ++k) {
        long long i = base + k;
        if (i < L) data[i] = toff + local[k];
    }
}

// Pass C: bucket-sort edges into ebuf as packed (local_row<<19 | col), dense appends
__global__ void k_scatter(const int* __restrict__ rows, const int* __restrict__ cols,
                          const int* __restrict__ off, unsigned* __restrict__ ebuf,
                          int nchunks, int NB, long long E) {
    extern __shared__ int cur[];
    for (int b = threadIdx.x; b < NB; b += blockDim.x)
        cur[b] = off[(long long)b * nchunks + blockIdx.x];
    __syncthreads();
    long long beg = (long long)blockIdx.x * CH;
    long long end = beg + CH; if (end > E) end = E;
    for (long long i = beg + threadIdx.x; i < end; i += blockDim.x) {
        int r = rows[i], c = cols[i];
        int p = atomicAdd(&cur[r >> BSH], 1);
        ebuf[p] = ((unsigned)(r & (BROWS - 1)) << CBITS) | (unsigned)c;
    }
}

// Pass D: one block per bucket — row degrees (LDS), block scan -> rp/dinv,
// then scatter cols into the bucket's contiguous colso window (single CU).
__global__ void k_finalize(const unsigned* __restrict__ ebuf, const int* __restrict__ off,
                           int* __restrict__ rp, float* __restrict__ dinv,
                           int* __restrict__ colso,
                           int nchunks, int NB, long long N, long long E) {
    __shared__ int deg[BROWS];
    __shared__ int cur[BROWS];
    __shared__ int s[256];
    const int b = blockIdx.x, t = threadIdx.x;
    const long long row0 = (long long)b << BSH;
    const int base = off[(long long)b * nchunks];
    const int bend = (b + 1 < NB) ? off[(long long)(b + 1) * nchunks] : (int)E;
    deg[t] = 0; deg[t + 256] = 0;
    __syncthreads();
    for (int i = base + t; i < bend; i += 256)
        atomicAdd(&deg[ebuf[i] >> CBITS], 1);
    __syncthreads();
    int d0 = deg[2 * t], d1 = deg[2 * t + 1];
    s[t] = d0 + d1;
    __syncthreads();
    for (int o = 1; o < 256; o <<= 1) {          // inclusive Hillis-Steele
        int v = (t >= o) ? s[t - o] : 0;
        __syncthreads();
        s[t] += v;
        __syncthreads();
    }
    int excl = s[t] - (d0 + d1);
    int p0 = base + excl, p1 = p0 + d0;
    cur[2 * t] = p0; cur[2 * t + 1] = p1;
    long long r0 = row0 + 2 * t, r1 = r0 + 1;
    if (r0 < N) { rp[r0] = p0; dinv[r0] = d0 > 0 ? rsqrtf((float)d0) : 0.0f; }
    if (r1 < N) { rp[r1] = p1; dinv[r1] = d1 > 0 ? rsqrtf((float)d1) : 0.0f; }
    if (b == 0 && t == 0) rp[N] = (int)E;
    __syncthreads();
    for (int i = base + t; i < bend; i += 256) {
        unsigned w = ebuf[i];
        int lr = (int)(w >> CBITS);
        int c  = (int)(w & CMASK);
        int p = atomicAdd(&cur[lr], 1);
        colso[p] = c;
    }
}

// ============================ fused CSR SpMM ============================
// MODE 0: gather from concat(ue,ie); dst = s; acc = emb_row + s   (layer 1)
// MODE 1: gather from src;           dst = s; acc += s            (layer 2)
// MODE 2: gather from src;           no dst;  acc = (acc+s)*scale (layer 3)
template<int MODE>
__global__ void k_spmm(const int* __restrict__ rp, const int* __restrict__ colso,
                       const float* __restrict__ dinv,
                       const float* __restrict__ src,
                       const float* __restrict__ ue, const float* __restrict__ ie,
                       float* __restrict__ dst, float* __restrict__ accb,
                       long long N, long long NU, float scale) {
    const int lane = threadIdx.x & 63;
    long long row = (long long)blockIdx.x * (blockDim.x >> 6) + (threadIdx.x >> 6);
    if (row >= N) return;
    const int beg = rp[row], end = rp[row + 1];
    float s = 0.0f;
    for (int base = beg; base < end; base += 64) {
        int rem = end - base;
        int col = 0; float dc = 0.0f;
        if (lane < rem) { col = colso[base + lane]; dc = dinv[col]; }
        int m = rem < 64 ? rem : 64;
        for (int j = 0; j < m; ++j) {
            int   c = __shfl(col, j, 64);
            float w = __shfl(dc, j, 64);
            long long off = ((long long)c << 6) + lane;
            float g;
            if (MODE == 0) g = (c < (int)NU) ? ue[off] : ie[off - (NU << 6)];
            else           g = src[off];
            s = fmaf(w, g, s);
        }
    }
    s *= dinv[row];
    long long o = (row << 6) + lane;
    if (MODE == 0) {
        float e0 = (row < NU) ? ue[o] : ie[o - (NU << 6)];
        dst[o] = s;
        accb[o] = e0 + s;
    } else if (MODE == 1) {
        dst[o] = s;
        accb[o] += s;
    } else {
        accb[o] = (accb[o] + s) * scale;
    }
}

// ============================ fallback (atomic) ============================

__global__ void lgcn_init(const float4* __restrict__ ue, const float4* __restrict__ ie,
                          float4* __restrict__ cur, float4* __restrict__ acc,
                          long long n_user_v4, long long total_v4) {
    long long idx = (long long)blockIdx.x * blockDim.x + threadIdx.x;
    long long stride = (long long)gridDim.x * blockDim.x;
    for (long long i = idx; i < total_v4; i += stride) {
        float4 v = (i < n_user_v4) ? ue[i] : ie[i - n_user_v4];
        cur[i] = v; acc[i] = v;
    }
}

__global__ void lgcn_spmm(const float* __restrict__ vals, const int* __restrict__ rows,
                          const int* __restrict__ cols, const float* __restrict__ cur,
                          float* __restrict__ next, long long nE) {
    long long tid = (long long)blockIdx.x * blockDim.x + threadIdx.x;
    long long stride = (long long)gridDim.x * blockDim.x;
    long long total = nE << 6;
    for (long long i = tid; i < total; i += stride) {
        long long e = i >> 6;
        int d = (int)(i & 63);
        float m = vals[e] * cur[((long long)cols[e] << 6) + d];
        atomicAdd(&next[((long long)rows[e] << 6) + d], m);
    }
}

__global__ void lgcn_acc_add(float4* __restrict__ acc, const float4* __restrict__ nxt,
                             long long total_v4) {
    long long idx = (long long)blockIdx.x * blockDim.x + threadIdx.x;
    long long stride = (long long)gridDim.x * blockDim.x;
    for (long long i = idx; i < total_v4; i += stride) {
        float4 a = acc[i]; float4 b = nxt[i];
        a.x += b.x; a.y += b.y; a.z += b.z; a.w += b.w;
        acc[i] = a;
    }
}

__global__ void lgcn_acc_add_scale(float4* __restrict__ acc, const float4* __restrict__ nxt,
                                   float s, long long total_v4) {
    long long idx = (long long)blockIdx.x * blockDim.x + threadIdx.x;
    long long stride = (long long)gridDim.x * blockDim.x;
    for (long long i = idx; i < total_v4; i += stride) {
        float4 a = acc[i]; float4 b = nxt[i];
        a.x = (a.x + b.x) * s; a.y = (a.y + b.y) * s;
        a.z = (a.z + b.z) * s; a.w = (a.w + b.w) * s;
        acc[i] = a;
    }
}

// ============================ launch ============================

extern "C" void kernel_launch(void* const* d_in, const int* in_sizes, int n_in,
                              void* d_out, int out_size, void* d_ws, size_t ws_size,
                              hipStream_t stream) {
    const float* ue   = (const float*)d_in[0];
    const float* ie   = (const float*)d_in[1];
    const float* vals = (const float*)d_in[2];
    const int*   rows = (const int*)d_in[3];
    const int*   cols = (const int*)d_in[4];
    const int n_layers = 3;   // fixed by problem; grid shapes must be host-known

    const long long n_users = in_sizes[0] / DIM;
    const long long n_items = in_sizes[1] / DIM;
    const long long E       = in_sizes[2];
    const long long N       = n_users + n_items;
    const long long nElem   = N * DIM;
    const long long nV4     = nElem / 4;
    const long long nUserV4 = (n_users * DIM) / 4;

    float* acc = (float*)d_out;
    const int tb = 256;

    const int nchunks = (int)((E + CH - 1) / CH);
    const int NB      = (int)((N + BROWS - 1) / BROWS);
    const long long L = (long long)NB * nchunks;
    const int nbs     = (int)((L + SCAN_CHUNK - 1) / SCAN_CHUNK);

    // ws layout (ebuf overlays buf0 — dead before spmm writes buf0)
    size_t need = (size_t)(2 * nElem + E /*colso*/ + (N + 1) /*rp*/ + N /*dinv*/
                           + L + nbs + 64) * 4;

    if (ws_size >= need && N < (1LL << CBITS)) {
        char* p = (char*)d_ws;
        float* buf0  = (float*)p;                  p += (size_t)nElem * 4;
        float* buf1  = (float*)p;                  p += (size_t)nElem * 4;
        int*   colso = (int*)p;                    p += (size_t)E * 4;
        int*   rp    = (int*)p;                    p += (size_t)(N + 1) * 4;
        float* dinv  = (float*)p;                  p += (size_t)N * 4;
        int*   cnt   = (int*)p;                    p += (size_t)L * 4;
        int*   partials = (int*)p;
        unsigned* ebuf = (unsigned*)buf0;

        k_cnt<<<nchunks, tb, NB * 4, stream>>>(rows, cnt, nchunks, NB, E);
        k_scanA<<<nbs, SCAN_T, 0, stream>>>(cnt, partials, L);
        k_scanB<<<1, 64, 0, stream>>>(partials, nbs);
        k_scanC<<<nbs, SCAN_T, 0, stream>>>(cnt, partials, L);
        k_scatter<<<nchunks, tb, NB * 4, stream>>>(rows, cols, cnt, ebuf, nchunks, NB, E);
        k_finalize<<<NB, tb, 0, stream>>>(ebuf, cnt, rp, dinv, colso, nchunks, NB, N, E);

        const int WPB = tb / 64;
        const int gspmm = (int)((N + WPB - 1) / WPB);
        k_spmm<0><<<gspmm, tb, 0, stream>>>(rp, colso, dinv, nullptr, ue, ie,
                                            buf0, acc, N, n_users, 0.0f);
        k_spmm<1><<<gspmm, tb, 0, stream>>>(rp, colso, dinv, buf0, ue, ie,
                                            buf1, acc, N, n_users, 0.0f);
        k_spmm<2><<<gspmm, tb, 0, stream>>>(rp, colso, dinv, buf1, ue, ie,
                                            nullptr, acc, N, n_users,
                                            1.0f / (float)(n_layers + 1));
    } else {
        // fallback: atomic scatter path (round-1 kernel)
        float* cur = (float*)d_ws;
        float* nxt = cur + nElem;
        int gridInit = (int)((nV4 + tb - 1) / tb); if (gridInit > 4096) gridInit = 4096;
        lgcn_init<<<gridInit, tb, 0, stream>>>((const float4*)ue, (const float4*)ie,
                                               (float4*)cur, (float4*)acc, nUserV4, nV4);
        for (int l = 0; l < n_layers; ++l) {
            hipMemsetAsync(nxt, 0, (size_t)nElem * 4, stream);
            lgcn_spmm<<<8192, tb, 0, stream>>>(vals, rows, cols, cur, nxt, E);
            if (l == n_layers - 1) {
                lgcn_acc_add_scale<<<gridInit, tb, 0, stream>>>(
                    (float4*)acc, (const float4*)nxt, 1.0f / (float)(n_layers + 1), nV4);
            } else {
                lgcn_acc_add<<<gridInit, tb, 0, stream>>>((float4*)acc, (const float4*)nxt, nV4);
            }
            float* t = cur; cur = nxt; nxt = t;
        }
    }
}

// Round 4
// 551.630 us; speedup vs baseline: 4.8197x; 1.7443x over previous
//
#include <hip/hip_runtime.h>
#include <hip/hip_fp16.h>

#define DIM 64
#define CH 16384          // edges per chunk in sort passes
#define BROWS 512         // rows per bucket
#define BSH 9             // log2(BROWS)
#define CBITS 19          // bits for col index in packed word (N < 2^19)
#define CMASK ((1u << CBITS) - 1u)
#define SCAN_T 256
#define SCAN_I 16
#define SCAN_CHUNK (SCAN_T * SCAN_I)

// ===================== dense CSR build (counting sort) =====================

__global__ void k_cnt(const int* __restrict__ rows, int* __restrict__ cnt,
                      int nchunks, int NB, long long E) {
    extern __shared__ int hist[];
    for (int b = threadIdx.x; b < NB; b += blockDim.x) hist[b] = 0;
    __syncthreads();
    long long beg = (long long)blockIdx.x * CH;
    long long end = beg + CH; if (end > E) end = E;
    for (long long i = beg + threadIdx.x; i < end; i += blockDim.x)
        atomicAdd(&hist[rows[i] >> BSH], 1);
    __syncthreads();
    for (int b = threadIdx.x; b < NB; b += blockDim.x)
        cnt[(long long)b * nchunks + blockIdx.x] = hist[b];
}

__global__ void k_scanA(const int* __restrict__ in, int* __restrict__ partials, long long L) {
    long long base = (long long)blockIdx.x * SCAN_CHUNK + (long long)threadIdx.x * SCAN_I;
    int tsum = 0;
    for (int k = 0; k < SCAN_I; ++k) { long long i = base + k; if (i < L) tsum += in[i]; }
    __shared__ int s[SCAN_T];
    s[threadIdx.x] = tsum; __syncthreads();
    for (int o = SCAN_T / 2; o > 0; o >>= 1) {
        if (threadIdx.x < o) s[threadIdx.x] += s[threadIdx.x + o];
        __syncthreads();
    }
    if (threadIdx.x == 0) partials[blockIdx.x] = s[0];
}

__global__ void k_scanB(int* partials, int nb) {
    if (threadIdx.x == 0 && blockIdx.x == 0) {
        int run = 0;
        for (int i = 0; i < nb; ++i) { int v = partials[i]; partials[i] = run; run += v; }
    }
}

__global__ void k_scanC(int* __restrict__ data, const int* __restrict__ partials, long long L) {
    const int t = threadIdx.x;
    long long base = (long long)blockIdx.x * SCAN_CHUNK + (long long)t * SCAN_I;
    int local[SCAN_I]; int tsum = 0;
    for (int k = 0; k < SCAN_I; ++k) {
        long long i = base + k;
        int d = (i < L) ? data[i] : 0;
        local[k] = tsum; tsum += d;
    }
    __shared__ int s[SCAN_T];
    s[t] = tsum; __syncthreads();
    for (int o = 1; o < SCAN_T; o <<= 1) {
        int v = (t >= o) ? s[t - o] : 0;
        __syncthreads();
        s[t] += v;
        __syncthreads();
    }
    int toff = partials[blockIdx.x] + (s[t] - tsum);
    for (int k = 0; k < SCAN_I; ++k) {
        long long i = base + k;
        if (i < L) data[i] = toff + local[k];
    }
}

__global__ void k_scatter(const int* __restrict__ rows, const int* __restrict__ cols,
                          const int* __restrict__ off, unsigned* __restrict__ ebuf,
                          int nchunks, int NB, long long E) {
    extern __shared__ int cur[];
    for (int b = threadIdx.x; b < NB; b += blockDim.x)
        cur[b] = off[(long long)b * nchunks + blockIdx.x];
    __syncthreads();
    long long beg = (long long)blockIdx.x * CH;
    long long end = beg + CH; if (end > E) end = E;
    for (long long i = beg + threadIdx.x; i < end; i += blockDim.x) {
        int r = rows[i], c = cols[i];
        int p = atomicAdd(&cur[r >> BSH], 1);
        ebuf[p] = ((unsigned)(r & (BROWS - 1)) << CBITS) | (unsigned)c;
    }
}

__global__ void k_finalize(const unsigned* __restrict__ ebuf, const int* __restrict__ off,
                           int* __restrict__ rp, float* __restrict__ dinv,
                           int* __restrict__ colso,
                           int nchunks, int NB, long long N, long long E) {
    __shared__ int deg[BROWS];
    __shared__ int cur[BROWS];
    __shared__ int s[256];
    const int b = blockIdx.x, t = threadIdx.x;
    const long long row0 = (long long)b << BSH;
    const int base = off[(long long)b * nchunks];
    const int bend = (b + 1 < NB) ? off[(long long)(b + 1) * nchunks] : (int)E;
    deg[t] = 0; deg[t + 256] = 0;
    __syncthreads();
    for (int i = base + t; i < bend; i += 256)
        atomicAdd(&deg[ebuf[i] >> CBITS], 1);
    __syncthreads();
    int d0 = deg[2 * t], d1 = deg[2 * t + 1];
    s[t] = d0 + d1;
    __syncthreads();
    for (int o = 1; o < 256; o <<= 1) {
        int v = (t >= o) ? s[t - o] : 0;
        __syncthreads();
        s[t] += v;
        __syncthreads();
    }
    int excl = s[t] - (d0 + d1);
    int p0 = base + excl, p1 = p0 + d0;
    cur[2 * t] = p0; cur[2 * t + 1] = p1;
    long long r0 = row0 + 2 * t, r1 = r0 + 1;
    if (r0 < N) { rp[r0] = p0; dinv[r0] = d0 > 0 ? rsqrtf((float)d0) : 0.0f; }
    if (r1 < N) { rp[r1] = p1; dinv[r1] = d1 > 0 ? rsqrtf((float)d1) : 0.0f; }
    if (b == 0 && t == 0) rp[N] = (int)E;
    __syncthreads();
    for (int i = base + t; i < bend; i += 256) {
        unsigned w = ebuf[i];
        int lr = (int)(w >> CBITS);
        int c  = (int)(w & CMASK);
        int p = atomicAdd(&cur[lr], 1);
        colso[p] = c;
    }
}

// y0 = D^-1/2 * concat(ue, ie), stored fp16 (half2-vectorized; 32 half2 per row)
__global__ void k_prep(const float2* __restrict__ ue2, const float2* __restrict__ ie2,
                       const float* __restrict__ dinv, __half2* __restrict__ yh,
                       long long NU2, long long total2) {
    long long i = (long long)blockIdx.x * blockDim.x + threadIdx.x;
    long long st = (long long)gridDim.x * blockDim.x;
    for (; i < total2; i += st) {
        float2 v = (i < NU2) ? ue2[i] : ie2[i - NU2];
        float d = dinv[i >> 5];
        yh[i] = __floats2half2_rn(v.x * d, v.y * d);
    }
}

// ============================ fused CSR SpMM ============================
// State: y = D^-1/2 x (fp16).  s[r] = sum_{c in N(r)} y[c]
//   x'[r] = dinv[r] * s;  y'[r] = s * dinv[r]^2
// MODE 0: acc = emb0 + x'; store y'    (layer 1)
// MODE 1: acc += x';       store y'    (layer 2)
// MODE 2: acc = (acc + x') * scale     (layer 3, no y' store)
template<int MODE>
__global__ void k_spmm(const int* __restrict__ rp, const int* __restrict__ colso,
                       const float* __restrict__ dinv,
                       const __half* __restrict__ src,
                       const float* __restrict__ ue, const float* __restrict__ ie,
                       __half* __restrict__ dsth, float* __restrict__ accb,
                       long long N, long long NU, float scale) {
    const int lane = threadIdx.x & 63;
    long long row = (long long)blockIdx.x * (blockDim.x >> 6) + (threadIdx.x >> 6);
    if (row >= N) return;
    const int beg = rp[row], end = rp[row + 1];
    float s = 0.0f;
    for (int base = beg; base < end; base += 64) {
        int rem = end - base;
        int col = 0;
        if (lane < rem) col = colso[base + lane];
        int m = rem < 64 ? rem : 64;
        float a0 = 0.f, a1 = 0.f, a2 = 0.f, a3 = 0.f;
        int j = 0;
        for (; j + 3 < m; j += 4) {
            int c0 = __shfl(col, j, 64);
            int c1 = __shfl(col, j + 1, 64);
            int c2 = __shfl(col, j + 2, 64);
            int c3 = __shfl(col, j + 3, 64);
            a0 += __half2float(src[((long long)c0 << 6) + lane]);
            a1 += __half2float(src[((long long)c1 << 6) + lane]);
            a2 += __half2float(src[((long long)c2 << 6) + lane]);
            a3 += __half2float(src[((long long)c3 << 6) + lane]);
        }
        for (; j < m; ++j) {
            int c = __shfl(col, j, 64);
            a0 += __half2float(src[((long long)c << 6) + lane]);
        }
        s += (a0 + a1) + (a2 + a3);
    }
    float dr = dinv[row];
    float x = s * dr;
    long long o = (row << 6) + lane;
    if (MODE == 0) {
        float e0 = (row < NU) ? ue[o] : ie[o - (NU << 6)];
        accb[o] = e0 + x;
        dsth[o] = __float2half(x * dr);
    } else if (MODE == 1) {
        accb[o] += x;
        dsth[o] = __float2half(x * dr);
    } else {
        accb[o] = (accb[o] + x) * scale;
    }
}

// ============================ fallback (atomic) ============================

__global__ void lgcn_init(const float4* __restrict__ ue, const float4* __restrict__ ie,
                          float4* __restrict__ cur, float4* __restrict__ acc,
                          long long n_user_v4, long long total_v4) {
    long long idx = (long long)blockIdx.x * blockDim.x + threadIdx.x;
    long long stride = (long long)gridDim.x * blockDim.x;
    for (long long i = idx; i < total_v4; i += stride) {
        float4 v = (i < n_user_v4) ? ue[i] : ie[i - n_user_v4];
        cur[i] = v; acc[i] = v;
    }
}

__global__ void lgcn_spmm(const float* __restrict__ vals, const int* __restrict__ rows,
                          const int* __restrict__ cols, const float* __restrict__ cur,
                          float* __restrict__ next, long long nE) {
    long long tid = (long long)blockIdx.x * blockDim.x + threadIdx.x;
    long long stride = (long long)gridDim.x * blockDim.x;
    long long total = nE << 6;
    for (long long i = tid; i < total; i += stride) {
        long long e = i >> 6;
        int d = (int)(i & 63);
        float m = vals[e] * cur[((long long)cols[e] << 6) + d];
        atomicAdd(&next[((long long)rows[e] << 6) + d], m);
    }
}

__global__ void lgcn_acc_add(float4* __restrict__ acc, const float4* __restrict__ nxt,
                             long long total_v4) {
    long long idx = (long long)blockIdx.x * blockDim.x + threadIdx.x;
    long long stride = (long long)gridDim.x * blockDim.x;
    for (long long i = idx; i < total_v4; i += stride) {
        float4 a = acc[i]; float4 b = nxt[i];
        a.x += b.x; a.y += b.y; a.z += b.z; a.w += b.w;
        acc[i] = a;
    }
}

__global__ void lgcn_acc_add_scale(float4* __restrict__ acc, const float4* __restrict__ nxt,
                                   float s, long long total_v4) {
    long long idx = (long long)blockIdx.x * blockDim.x + threadIdx.x;
    long long stride = (long long)gridDim.x * blockDim.x;
    for (long long i = idx; i < total_v4; i += stride) {
        float4 a = acc[i]; float4 b = nxt[i];
        a.x = (a.x + b.x) * s; a.y = (a.y + b.y) * s;
        a.z = (a.z + b.z) * s; a.w = (a.w + b.w) * s;
        acc[i] = a;
    }
}

// ============================ launch ============================

extern "C" void kernel_launch(void* const* d_in, const int* in_sizes, int n_in,
                              void* d_out, int out_size, void* d_ws, size_t ws_size,
                              hipStream_t stream) {
    const float* ue   = (const float*)d_in[0];
    const float* ie   = (const float*)d_in[1];
    const float* vals = (const float*)d_in[2];
    const int*   rows = (const int*)d_in[3];
    const int*   cols = (const int*)d_in[4];
    const int n_layers = 3;   // fixed by problem; grid shapes must be host-known

    const long long n_users = in_sizes[0] / DIM;
    const long long n_items = in_sizes[1] / DIM;
    const long long E       = in_sizes[2];
    const long long N       = n_users + n_items;
    const long long nElem   = N * DIM;
    const long long nV4     = nElem / 4;
    const long long nUserV4 = (n_users * DIM) / 4;

    float* acc = (float*)d_out;
    const int tb = 256;

    const int nchunks = (int)((E + CH - 1) / CH);
    const int NB      = (int)((N + BROWS - 1) / BROWS);
    const long long L = (long long)NB * nchunks;
    const int nbs     = (int)((L + SCAN_CHUNK - 1) / SCAN_CHUNK);

    // ws: yh0, yh1 (fp16), colso, rp, dinv, cnt, partials. ebuf overlays yh0.
    size_t need = (size_t)nElem * 2 * 2
                + (size_t)(E + (N + 1) + N + L + nbs + 64) * 4;

    if (ws_size >= need && N < (1LL << CBITS)) {
        char* p = (char*)d_ws;
        __half* yh0  = (__half*)p;                 p += (size_t)nElem * 2;
        __half* yh1  = (__half*)p;                 p += (size_t)nElem * 2;
        int*   colso = (int*)p;                    p += (size_t)E * 4;
        int*   rp    = (int*)p;                    p += (size_t)(N + 1) * 4;
        float* dinv  = (float*)p;                  p += (size_t)N * 4;
        int*   cnt   = (int*)p;                    p += (size_t)L * 4;
        int*   partials = (int*)p;
        unsigned* ebuf = (unsigned*)yh0;           // dead before k_prep writes yh0

        k_cnt<<<nchunks, tb, NB * 4, stream>>>(rows, cnt, nchunks, NB, E);
        k_scanA<<<nbs, SCAN_T, 0, stream>>>(cnt, partials, L);
        k_scanB<<<1, 64, 0, stream>>>(partials, nbs);
        k_scanC<<<nbs, SCAN_T, 0, stream>>>(cnt, partials, L);
        k_scatter<<<nchunks, tb, NB * 4, stream>>>(rows, cols, cnt, ebuf, nchunks, NB, E);
        k_finalize<<<NB, tb, 0, stream>>>(ebuf, cnt, rp, dinv, colso, nchunks, NB, N, E);

        long long total2 = nElem / 2, NU2 = n_users * (DIM / 2);
        int gprep = (int)((total2 + tb - 1) / tb); if (gprep > 4096) gprep = 4096;
        k_prep<<<gprep, tb, 0, stream>>>((const float2*)ue, (const float2*)ie,
                                         dinv, (__half2*)yh0, NU2, total2);

        const int WPB = tb / 64;
        const int gspmm = (int)((N + WPB - 1) / WPB);
        k_spmm<0><<<gspmm, tb, 0, stream>>>(rp, colso, dinv, yh0, ue, ie,
                                            yh1, acc, N, n_users, 0.0f);
        k_spmm<1><<<gspmm, tb, 0, stream>>>(rp, colso, dinv, yh1, ue, ie,
                                            yh0, acc, N, n_users, 0.0f);
        k_spmm<2><<<gspmm, tb, 0, stream>>>(rp, colso, dinv, yh0, ue, ie,
                                            nullptr, acc, N, n_users,
                                            1.0f / (float)(n_layers + 1));
    } else {
        // fallback: atomic scatter path (round-1 kernel)
        float* cur = (float*)d_ws;
        float* nxt = cur + nElem;
        int gridInit = (int)((nV4 + tb - 1) / tb); if (gridInit > 4096) gridInit = 4096;
        lgcn_init<<<gridInit, tb, 0, stream>>>((const float4*)ue, (const float4*)ie,
                                               (float4*)cur, (float4*)acc, nUserV4, nV4);
        for (int l = 0; l < n_layers; ++l) {
            hipMemsetAsync(nxt, 0, (size_t)nElem * 4, stream);
            lgcn_spmm<<<8192, tb, 0, stream>>>(vals, rows, cols, cur, nxt, E);
            if (l == n_layers - 1) {
                lgcn_acc_add_scale<<<gridInit, tb, 0, stream>>>(
                    (float4*)acc, (const float4*)nxt, 1.0f / (float)(n_layers + 1), nV4);
            } else {
                lgcn_acc_add<<<gridInit, tb, 0, stream>>>((float4*)acc, (const float4*)nxt, nV4);
            }
            float* t = cur; cur = nxt; nxt = t;
        }
    }
}

// Round 5
// 512.769 us; speedup vs baseline: 5.1850x; 1.0758x over previous
//
#include <hip/hip_runtime.h>
#include <hip/hip_fp16.h>

#define DIM 64
#define CH 16384          // edges per chunk in sort passes
#define BROWS 512         // rows per bucket
#define BSH 9             // log2(BROWS)
#define CBITS 19          // bits for col index in packed word (N < 2^19)
#define CMASK ((1u << CBITS) - 1u)
#define SCAN_T 256
#define SCAN_I 16
#define SCAN_CHUNK (SCAN_T * SCAN_I)

// ===================== dense CSR build (counting sort) =====================

__global__ void k_cnt(const int* __restrict__ rows, int* __restrict__ cnt,
                      int nchunks, int NB, long long E) {
    extern __shared__ int hist[];
    for (int b = threadIdx.x; b < NB; b += blockDim.x) hist[b] = 0;
    __syncthreads();
    long long beg = (long long)blockIdx.x * CH;
    long long end = beg + CH; if (end > E) end = E;
    for (long long i = beg + threadIdx.x; i < end; i += blockDim.x)
        atomicAdd(&hist[rows[i] >> BSH], 1);
    __syncthreads();
    for (int b = threadIdx.x; b < NB; b += blockDim.x)
        cnt[(long long)b * nchunks + blockIdx.x] = hist[b];
}

__global__ void k_scanA(const int* __restrict__ in, int* __restrict__ partials, long long L) {
    long long base = (long long)blockIdx.x * SCAN_CHUNK + (long long)threadIdx.x * SCAN_I;
    int tsum = 0;
    for (int k = 0; k < SCAN_I; ++k) { long long i = base + k; if (i < L) tsum += in[i]; }
    __shared__ int s[SCAN_T];
    s[threadIdx.x] = tsum; __syncthreads();
    for (int o = SCAN_T / 2; o > 0; o >>= 1) {
        if (threadIdx.x < o) s[threadIdx.x] += s[threadIdx.x + o];
        __syncthreads();
    }
    if (threadIdx.x == 0) partials[blockIdx.x] = s[0];
}

__global__ void k_scanB(int* partials, int nb) {
    if (threadIdx.x == 0 && blockIdx.x == 0) {
        int run = 0;
        for (int i = 0; i < nb; ++i) { int v = partials[i]; partials[i] = run; run += v; }
    }
}

__global__ void k_scanC(int* __restrict__ data, const int* __restrict__ partials, long long L) {
    const int t = threadIdx.x;
    long long base = (long long)blockIdx.x * SCAN_CHUNK + (long long)t * SCAN_I;
    int local[SCAN_I]; int tsum = 0;
    for (int k = 0; k < SCAN_I; ++k) {
        long long i = base + k;
        int d = (i < L) ? data[i] : 0;
        local[k] = tsum; tsum += d;
    }
    __shared__ int s[SCAN_T];
    s[t] = tsum; __syncthreads();
    for (int o = 1; o < SCAN_T; o <<= 1) {
        int v = (t >= o) ? s[t - o] : 0;
        __syncthreads();
        s[t] += v;
        __syncthreads();
    }
    int toff = partials[blockIdx.x] + (s[t] - tsum);
    for (int k = 0; k < SCAN_I; ++k) {
        long long i = base + k;
        if (i < L) data[i] = toff + local[k];
    }
}

__global__ void k_scatter(const int* __restrict__ rows, const int* __restrict__ cols,
                          const int* __restrict__ off, unsigned* __restrict__ ebuf,
                          int nchunks, int NB, long long E) {
    extern __shared__ int cur[];
    for (int b = threadIdx.x; b < NB; b += blockDim.x)
        cur[b] = off[(long long)b * nchunks + blockIdx.x];
    __syncthreads();
    long long beg = (long long)blockIdx.x * CH;
    long long end = beg + CH; if (end > E) end = E;
    for (long long i = beg + threadIdx.x; i < end; i += blockDim.x) {
        int r = rows[i], c = cols[i];
        int p = atomicAdd(&cur[r >> BSH], 1);
        ebuf[p] = ((unsigned)(r & (BROWS - 1)) << CBITS) | (unsigned)c;
    }
}

__global__ void k_finalize(const unsigned* __restrict__ ebuf, const int* __restrict__ off,
                           int* __restrict__ rp, float* __restrict__ dinv,
                           float* __restrict__ dsq, int* __restrict__ colso,
                           int nchunks, int NB, long long N, long long E) {
    __shared__ int deg[BROWS];
    __shared__ int cur[BROWS];
    __shared__ int s[256];
    const int b = blockIdx.x, t = threadIdx.x;
    const long long row0 = (long long)b << BSH;
    const int base = off[(long long)b * nchunks];
    const int bend = (b + 1 < NB) ? off[(long long)(b + 1) * nchunks] : (int)E;
    deg[t] = 0; deg[t + 256] = 0;
    __syncthreads();
    for (int i = base + t; i < bend; i += 256)
        atomicAdd(&deg[ebuf[i] >> CBITS], 1);
    __syncthreads();
    int d0 = deg[2 * t], d1 = deg[2 * t + 1];
    s[t] = d0 + d1;
    __syncthreads();
    for (int o = 1; o < 256; o <<= 1) {
        int v = (t >= o) ? s[t - o] : 0;
        __syncthreads();
        s[t] += v;
        __syncthreads();
    }
    int excl = s[t] - (d0 + d1);
    int p0 = base + excl, p1 = p0 + d0;
    cur[2 * t] = p0; cur[2 * t + 1] = p1;
    long long r0 = row0 + 2 * t, r1 = r0 + 1;
    if (r0 < N) {
        rp[r0] = p0;
        dinv[r0] = d0 > 0 ? rsqrtf((float)d0) : 0.0f;
        dsq[r0]  = sqrtf((float)d0);
    }
    if (r1 < N) {
        rp[r1] = p1;
        dinv[r1] = d1 > 0 ? rsqrtf((float)d1) : 0.0f;
        dsq[r1]  = sqrtf((float)d1);
    }
    if (b == 0 && t == 0) rp[N] = (int)E;
    __syncthreads();
    for (int i = base + t; i < bend; i += 256) {
        unsigned w = ebuf[i];
        int lr = (int)(w >> CBITS);
        int c  = (int)(w & CMASK);
        int p = atomicAdd(&cur[lr], 1);
        colso[p] = c;
    }
}

// y0 = D^-1/2 * concat(ue, ie), fp16; float4 in -> 2x half2 (8B) out
__global__ void k_prep(const float4* __restrict__ ue4, const float4* __restrict__ ie4,
                       const float* __restrict__ dinv, int2* __restrict__ yh4,
                       long long NU4, long long total4) {
    long long i = (long long)blockIdx.x * blockDim.x + threadIdx.x;
    if (i >= total4) return;
    float4 v = (i < NU4) ? ue4[i] : ie4[i - NU4];
    float d = dinv[i >> 4];
    __half2 h01 = __floats2half2_rn(v.x * d, v.y * d);
    __half2 h23 = __floats2half2_rn(v.z * d, v.w * d);
    int2 w;
    w.x = *reinterpret_cast<int*>(&h01);
    w.y = *reinterpret_cast<int*>(&h23);
    yh4[i] = w;
}

// ============================ fused CSR SpMM ============================
// State y = D^-1/2 x (fp16).  s[r] = sum_{c in N(r)} y_src[c]
// FINAL==0: y_dst[r] = s * dinv[r]^2                       (layers 1,2)
// FINAL==1: acc[r] = (e0 + (y1+y2)*sqrt(deg) + s*dinv)*sc  (layer 3 fused)
// row is wave-uniform: readfirstlane -> scalar rp/colso loads (constant
// cache), gather = SGPR-base + lane voffset ushort loads.
template<int FINAL>
__global__ void k_spmm(const int* __restrict__ rp, const int* __restrict__ colso,
                       const float* __restrict__ dinv, const float* __restrict__ dsq,
                       const __half* __restrict__ src,
                       const __half* __restrict__ y1, const __half* __restrict__ y2,
                       const float* __restrict__ ue, const float* __restrict__ ie,
                       __half* __restrict__ dsth, float* __restrict__ accb,
                       long long N, long long NU, float scale) {
    const int lane = threadIdx.x & 63;
    long long row0 = (long long)blockIdx.x * (blockDim.x >> 6) + (threadIdx.x >> 6);
    if (row0 >= N) return;
    const int rs  = __builtin_amdgcn_readfirstlane((int)row0);
    const int beg = rp[rs];
    const int end = rp[rs + 1];
    const long long o = ((long long)rs << 6) + lane;

    // issue dense epilogue loads early (hidden under gather loop)
    float e0 = 0.f, yv = 0.f, q = 0.f;
    if (FINAL) {
        e0 = (rs < (int)NU) ? ue[o] : ie[o - (NU << 6)];
        yv = __half2float(y1[o]) + __half2float(y2[o]);
        q  = dsq[rs];
    }

    float a0 = 0.f, a1 = 0.f, a2 = 0.f, a3 = 0.f;
    int j = beg;
    for (; j + 8 <= end; j += 8) {
        int c0 = colso[j + 0], c1 = colso[j + 1], c2 = colso[j + 2], c3 = colso[j + 3];
        int c4 = colso[j + 4], c5 = colso[j + 5], c6 = colso[j + 6], c7 = colso[j + 7];
        a0 += __half2float(src[((long long)c0 << 6) + lane]);
        a1 += __half2float(src[((long long)c1 << 6) + lane]);
        a2 += __half2float(src[((long long)c2 << 6) + lane]);
        a3 += __half2float(src[((long long)c3 << 6) + lane]);
        a0 += __half2float(src[((long long)c4 << 6) + lane]);
        a1 += __half2float(src[((long long)c5 << 6) + lane]);
        a2 += __half2float(src[((long long)c6 << 6) + lane]);
        a3 += __half2float(src[((long long)c7 << 6) + lane]);
    }
    for (; j < end; ++j)
        a0 += __half2float(src[((long long)colso[j] << 6) + lane]);
    float s  = (a0 + a1) + (a2 + a3);
    float dr = dinv[rs];
    if (!FINAL) {
        dsth[o] = __float2half(s * dr * dr);
    } else {
        accb[o] = (e0 + yv * q + s * dr) * scale;
    }
}

// ============================ fallback (atomic) ============================

__global__ void lgcn_init(const float4* __restrict__ ue, const float4* __restrict__ ie,
                          float4* __restrict__ cur, float4* __restrict__ acc,
                          long long n_user_v4, long long total_v4) {
    long long idx = (long long)blockIdx.x * blockDim.x + threadIdx.x;
    long long stride = (long long)gridDim.x * blockDim.x;
    for (long long i = idx; i < total_v4; i += stride) {
        float4 v = (i < n_user_v4) ? ue[i] : ie[i - n_user_v4];
        cur[i] = v; acc[i] = v;
    }
}

__global__ void lgcn_spmm(const float* __restrict__ vals, const int* __restrict__ rows,
                          const int* __restrict__ cols, const float* __restrict__ cur,
                          float* __restrict__ next, long long nE) {
    long long tid = (long long)blockIdx.x * blockDim.x + threadIdx.x;
    long long stride = (long long)gridDim.x * blockDim.x;
    long long total = nE << 6;
    for (long long i = tid; i < total; i += stride) {
        long long e = i >> 6;
        int d = (int)(i & 63);
        float m = vals[e] * cur[((long long)cols[e] << 6) + d];
        atomicAdd(&next[((long long)rows[e] << 6) + d], m);
    }
}

__global__ void lgcn_acc_add(float4* __restrict__ acc, const float4* __restrict__ nxt,
                             long long total_v4) {
    long long idx = (long long)blockIdx.x * blockDim.x + threadIdx.x;
    long long stride = (long long)gridDim.x * blockDim.x;
    for (long long i = idx; i < total_v4; i += stride) {
        float4 a = acc[i]; float4 b = nxt[i];
        a.x += b.x; a.y += b.y; a.z += b.z; a.w += b.w;
        acc[i] = a;
    }
}

__global__ void lgcn_acc_add_scale(float4* __restrict__ acc, const float4* __restrict__ nxt,
                                   float s, long long total_v4) {
    long long idx = (long long)blockIdx.x * blockDim.x + threadIdx.x;
    long long stride = (long long)gridDim.x * blockDim.x;
    for (long long i = idx; i < total_v4; i += stride) {
        float4 a = acc[i]; float4 b = nxt[i];
        a.x = (a.x + b.x) * s; a.y = (a.y + b.y) * s;
        a.z = (a.z + b.z) * s; a.w = (a.w + b.w) * s;
        acc[i] = a;
    }
}

// ============================ launch ============================

extern "C" void kernel_launch(void* const* d_in, const int* in_sizes, int n_in,
                              void* d_out, int out_size, void* d_ws, size_t ws_size,
                              hipStream_t stream) {
    const float* ue   = (const float*)d_in[0];
    const float* ie   = (const float*)d_in[1];
    const float* vals = (const float*)d_in[2];
    const int*   rows = (const int*)d_in[3];
    const int*   cols = (const int*)d_in[4];
    const int n_layers = 3;   // fixed by problem; grid shapes must be host-known

    const long long n_users = in_sizes[0] / DIM;
    const long long n_items = in_sizes[1] / DIM;
    const long long E       = in_sizes[2];
    const long long N       = n_users + n_items;
    const long long nElem   = N * DIM;
    const long long nV4     = nElem / 4;
    const long long nUserV4 = (n_users * DIM) / 4;

    float* acc = (float*)d_out;
    const int tb = 256;

    const int nchunks = (int)((E + CH - 1) / CH);
    const int NB      = (int)((N + BROWS - 1) / BROWS);
    const long long L = (long long)NB * nchunks;
    const int nbs     = (int)((L + SCAN_CHUNK - 1) / SCAN_CHUNK);

    // ws: yh0,yh1,yh2 (fp16), colso, rp, dinv, dsq, cnt, partials. ebuf overlays yh0.
    size_t need = (size_t)nElem * 2 * 3
                + (size_t)(E + (N + 1) + 2 * N + L + nbs + 64) * 4;

    if (ws_size >= need && N < (1LL << CBITS)) {
        char* p = (char*)d_ws;
        __half* yh0  = (__half*)p;                 p += (size_t)nElem * 2;
        __half* yh1  = (__half*)p;                 p += (size_t)nElem * 2;
        __half* yh2  = (__half*)p;                 p += (size_t)nElem * 2;
        int*   colso = (int*)p;                    p += (size_t)E * 4;
        int*   rp    = (int*)p;                    p += (size_t)(N + 1) * 4;
        float* dinv  = (float*)p;                  p += (size_t)N * 4;
        float* dsq   = (float*)p;                  p += (size_t)N * 4;
        int*   cnt   = (int*)p;                    p += (size_t)L * 4;
        int*   partials = (int*)p;
        unsigned* ebuf = (unsigned*)yh0;           // dead before k_prep writes yh0

        k_cnt<<<nchunks, tb, NB * 4, stream>>>(rows, cnt, nchunks, NB, E);
        k_scanA<<<nbs, SCAN_T, 0, stream>>>(cnt, partials, L);
        k_scanB<<<1, 64, 0, stream>>>(partials, nbs);
        k_scanC<<<nbs, SCAN_T, 0, stream>>>(cnt, partials, L);
        k_scatter<<<nchunks, tb, NB * 4, stream>>>(rows, cols, cnt, ebuf, nchunks, NB, E);
        k_finalize<<<NB, tb, 0, stream>>>(ebuf, cnt, rp, dinv, dsq, colso, nchunks, NB, N, E);

        long long total4 = nElem / 4, NU4 = n_users * (DIM / 4);
        int gprep = (int)((total4 + tb - 1) / tb);
        k_prep<<<gprep, tb, 0, stream>>>((const float4*)ue, (const float4*)ie,
                                         dinv, (int2*)yh0, NU4, total4);

        const int WPB = tb / 64;
        const int gspmm = (int)((N + WPB - 1) / WPB);
        // layer 1: y0 -> y1
        k_spmm<0><<<gspmm, tb, 0, stream>>>(rp, colso, dinv, dsq, yh0,
                                            nullptr, nullptr, nullptr, nullptr,
                                            yh1, nullptr, N, n_users, 0.0f);
        // layer 2: y1 -> y2
        k_spmm<0><<<gspmm, tb, 0, stream>>>(rp, colso, dinv, dsq, yh1,
                                            nullptr, nullptr, nullptr, nullptr,
                                            yh2, nullptr, N, n_users, 0.0f);
        // layer 3 fused final: gather y2; acc = (e0 + (y1+y2)*dsq + s*dinv)/4
        k_spmm<1><<<gspmm, tb, 0, stream>>>(rp, colso, dinv, dsq, yh2,
                                            yh1, yh2, ue, ie,
                                            nullptr, acc, N, n_users,
                                            1.0f / (float)(n_layers + 1));
    } else {
        // fallback: atomic scatter path (round-1 kernel)
        float* cur = (float*)d_ws;
        float* nxt = cur + nElem;
        int gridInit = (int)((nV4 + tb - 1) / tb); if (gridInit > 4096) gridInit = 4096;
        lgcn_init<<<gridInit, tb, 0, stream>>>((const float4*)ue, (const float4*)ie,
                                               (float4*)cur, (float4*)acc, nUserV4, nV4);
        for (int l = 0; l < n_layers; ++l) {
            hipMemsetAsync(nxt, 0, (size_t)nElem * 4, stream);
            lgcn_spmm<<<8192, tb, 0, stream>>>(vals, rows, cols, cur, nxt, E);
            if (l == n_layers - 1) {
                lgcn_acc_add_scale<<<gridInit, tb, 0, stream>>>(
                    (float4*)acc, (const float4*)nxt, 1.0f / (float)(n_layers + 1), nV4);
            } else {
                lgcn_acc_add<<<gridInit, tb, 0, stream>>>((float4*)acc, (const float4*)nxt, nV4);
            }
            float* t = cur; cur = nxt; nxt = t;
        }
    }
}